// Round 1
// 444.000 us; speedup vs baseline: 1.2094x; 1.2094x over previous
//
#include <hip/hip_runtime.h>
#include <stdint.h>

#define cN0 100000
#define cN1 150000
#define cN2 50000
#define cNNZ00 1600000
#define cNNZ12 200000
#define cD 128

#define BROWS_LOG 9
#define BROWS 512
#define PBLK_E 8192
#define FCAP 10240
#define CAP00 10240   // bucket slab capacity graph 0->0 (mean 8192, sigma~90)
#define CAP12 3072    // bucket slab capacity graph 1->2 (mean 2041, sigma~45)

#define NB0 196       // ceil(cN0/512)
#define NB2 98        // ceil(cN2/512)
#define PB0 ((cNNZ00 + PBLK_E - 1) / PBLK_E)   // 196
#define PB1 ((cNNZ12 + PBLK_E - 1) / PBLK_E)   // 25
#define GB12 ((cN1 + 127) / 128)               // 1172
#define GB00 ((cN0 + 127) / 128)               // 782

typedef __attribute__((ext_vector_type(8))) short short8;
typedef __attribute__((ext_vector_type(4))) float f32x4;

__device__ __forceinline__ uint16_t f2bf(float f) {
    uint32_t u = __float_as_uint(f);
    u += 0x7fffu + ((u >> 16) & 1u);
    return (uint16_t)(u >> 16);
}
__device__ __forceinline__ float bf2f(uint32_t lo16) {
    return __uint_as_float(lo16 << 16);
}

// ---------------- Fused MFMA GEMM: both graphs in one dispatch ---------------
// blocks [0, GB12)        : h12 = bf16(relu(x1) @ W12), relu1 = relu(x1)
// blocks [GB12, GB12+GB00): h0  = bf16(relu(x0) @ W0)
__global__ __launch_bounds__(256) void gemm_fused_kernel(
    const float* __restrict__ x1, const float* __restrict__ W12,
    uint16_t* __restrict__ h12, float* __restrict__ relu1,
    const float* __restrict__ x0, const float* __restrict__ W0,
    uint16_t* __restrict__ h0)
{
    __shared__ __align__(16) uint16_t Bpack[cD * cD];   // 32 KB

    const float* x; const float* W; uint16_t* h; float* relu_out;
    int nrows, bb; bool wr;
    if ((int)blockIdx.x < GB12) {
        x = x1; W = W12; h = h12; relu_out = relu1; nrows = cN1;
        bb = blockIdx.x; wr = true;
    } else {
        x = x0; W = W0; h = h0; relu_out = nullptr; nrows = cN0;
        bb = blockIdx.x - GB12; wr = false;
    }

    const int tid = threadIdx.x;
    for (int i = tid * 4; i < cD * cD; i += 1024) {
        int k = i >> 7, c = i & 127;
        float4 w = *(const float4*)&W[i];
        int kt = k >> 5, q = (k >> 3) & 3, j = k & 7;
        uint16_t b[4] = { f2bf(w.x), f2bf(w.y), f2bf(w.z), f2bf(w.w) };
        #pragma unroll
        for (int t = 0; t < 4; ++t) {
            int cc = c + t, ct = cc >> 4, n = cc & 15;
            Bpack[(((kt * 8 + ct) * 64) + q * 16 + n) * 8 + j] = b[t];
        }
    }
    __syncthreads();

    const int wid = tid >> 6, l = tid & 63;
    const int rb = bb * 128 + wid * 32;
    const int m = l & 15, q = l >> 4;
    const int r0 = rb + m, r1 = rb + 16 + m;

    f32x4 acc[2][8];
    #pragma unroll
    for (int rt = 0; rt < 2; ++rt)
        #pragma unroll
        for (int ct = 0; ct < 8; ++ct)
            acc[rt][ct] = (f32x4){0.f, 0.f, 0.f, 0.f};

    for (int kt = 0; kt < 4; ++kt) {
        const int k0 = kt * 32 + q * 8;
        float4 xa0 = make_float4(0.f,0.f,0.f,0.f), xa1 = xa0;
        float4 xb0 = xa0, xb1 = xa0;
        if (r0 < nrows) {
            xa0 = *(const float4*)&x[(size_t)r0 * cD + k0];
            xa1 = *(const float4*)&x[(size_t)r0 * cD + k0 + 4];
        }
        if (r1 < nrows) {
            xb0 = *(const float4*)&x[(size_t)r1 * cD + k0];
            xb1 = *(const float4*)&x[(size_t)r1 * cD + k0 + 4];
        }
        xa0.x=fmaxf(xa0.x,0.f); xa0.y=fmaxf(xa0.y,0.f); xa0.z=fmaxf(xa0.z,0.f); xa0.w=fmaxf(xa0.w,0.f);
        xa1.x=fmaxf(xa1.x,0.f); xa1.y=fmaxf(xa1.y,0.f); xa1.z=fmaxf(xa1.z,0.f); xa1.w=fmaxf(xa1.w,0.f);
        xb0.x=fmaxf(xb0.x,0.f); xb0.y=fmaxf(xb0.y,0.f); xb0.z=fmaxf(xb0.z,0.f); xb0.w=fmaxf(xb0.w,0.f);
        xb1.x=fmaxf(xb1.x,0.f); xb1.y=fmaxf(xb1.y,0.f); xb1.z=fmaxf(xb1.z,0.f); xb1.w=fmaxf(xb1.w,0.f);
        if (wr) {
            if (r0 < nrows) {
                *(float4*)&relu_out[(size_t)r0 * cD + k0]     = xa0;
                *(float4*)&relu_out[(size_t)r0 * cD + k0 + 4] = xa1;
            }
            if (r1 < nrows) {
                *(float4*)&relu_out[(size_t)r1 * cD + k0]     = xb0;
                *(float4*)&relu_out[(size_t)r1 * cD + k0 + 4] = xb1;
            }
        }
        short8 a0, a1;
        a0[0]=(short)f2bf(xa0.x); a0[1]=(short)f2bf(xa0.y); a0[2]=(short)f2bf(xa0.z); a0[3]=(short)f2bf(xa0.w);
        a0[4]=(short)f2bf(xa1.x); a0[5]=(short)f2bf(xa1.y); a0[6]=(short)f2bf(xa1.z); a0[7]=(short)f2bf(xa1.w);
        a1[0]=(short)f2bf(xb0.x); a1[1]=(short)f2bf(xb0.y); a1[2]=(short)f2bf(xb0.z); a1[3]=(short)f2bf(xb0.w);
        a1[4]=(short)f2bf(xb1.x); a1[5]=(short)f2bf(xb1.y); a1[6]=(short)f2bf(xb1.z); a1[7]=(short)f2bf(xb1.w);

        #pragma unroll
        for (int ct = 0; ct < 8; ++ct) {
            short8 bf = *(const short8*)&Bpack[((kt * 8 + ct) * 64 + l) * 8];
            acc[0][ct] = __builtin_amdgcn_mfma_f32_16x16x32_bf16(a0, bf, acc[0][ct], 0, 0, 0);
            acc[1][ct] = __builtin_amdgcn_mfma_f32_16x16x32_bf16(a1, bf, acc[1][ct], 0, 0, 0);
        }
    }

    #pragma unroll
    for (int rt = 0; rt < 2; ++rt) {
        #pragma unroll
        for (int i = 0; i < 4; ++i) {
            int row = rb + rt * 16 + q * 4 + i;
            if (row < nrows) {
                #pragma unroll
                for (int ct = 0; ct < 8; ++ct)
                    h[(size_t)row * cD + ct * 16 + m] = f2bf(acc[rt][ct][i]);
            }
        }
    }
}

// ---------------- Fused partition: 8192 edges/block -> fixed-capacity slabs --
// No histogram / scan pre-pass: bucket b owns slab [b*CAP, (b+1)*CAP), global
// cursors (bcur, zeroed) hand out offsets. Edge: .x=(row_local<<20)|col, .y=val
__global__ __launch_bounds__(256) void partition_fused(
    const int* __restrict__ r00, const int* __restrict__ c00, const float* __restrict__ v00,
    const int* __restrict__ r12, const int* __restrict__ c12, const float* __restrict__ v12,
    int* __restrict__ bcur0, int* __restrict__ bcur2,
    uint2* __restrict__ slab0, uint2* __restrict__ slab2)
{
    __shared__ uint2   sedge[PBLK_E];    // 64 KB
    __shared__ uint8_t sbkt[PBLK_E];     // 8 KB
    __shared__ int lcount[256], loffset[256], lcur[256], gbase[256];

    const int* rows; const int* cols; const float* vals;
    int nnz, nb, cap, bb; int* bcur; uint2* out;
    if ((int)blockIdx.x < PB0) {
        rows = r00; cols = c00; vals = v00; nnz = cNNZ00; nb = NB0; cap = CAP00;
        bcur = bcur0; out = slab0; bb = blockIdx.x;
    } else {
        rows = r12; cols = c12; vals = v12; nnz = cNNZ12; nb = NB2; cap = CAP12;
        bcur = bcur2; out = slab2; bb = blockIdx.x - PB0;
    }

    const int tid = threadIdx.x;
    const int base = bb * PBLK_E;
    const int count = min(PBLK_E, nnz - base);

    lcount[tid] = 0;
    __syncthreads();
    for (int i = tid; i < count; i += 256)
        atomicAdd(&lcount[rows[base + i] >> BROWS_LOG], 1);
    __syncthreads();

    int v = lcount[tid];
    loffset[tid] = v;
    __syncthreads();
    for (int o = 1; o < 256; o <<= 1) {
        int x = (tid >= o) ? loffset[tid - o] : 0;
        __syncthreads();
        loffset[tid] += x;
        __syncthreads();
    }
    int ex = loffset[tid] - v;
    __syncthreads();
    loffset[tid] = ex;
    lcur[tid] = ex;
    if (tid < nb && v > 0) gbase[tid] = atomicAdd(&bcur[tid], v);
    __syncthreads();

    for (int i = tid; i < count; i += 256) {
        int r = rows[base + i];
        uint32_t c = (uint32_t)cols[base + i];
        float w = vals[base + i];
        int b = r >> BROWS_LOG;
        int pos = atomicAdd(&lcur[b], 1);
        sedge[pos] = make_uint2(((uint32_t)(r & (BROWS - 1)) << 20) | c, __float_as_uint(w));
        sbkt[pos] = (uint8_t)b;
    }
    __syncthreads();

    for (int i = tid; i < count; i += 256) {
        int b = sbkt[i];
        int gpos = gbase[b] + (i - loffset[b]);
        if (gpos < cap)   // slab overflow guard (statistically unreachable)
            out[(size_t)b * cap + gpos] = sedge[i];
    }
}

// ---------------- Fused fine place: in-LDS counting sort per bucket ----------
// Emits explicit row_start/row_end (slabs are not contiguous across buckets).
__global__ __launch_bounds__(256) void fine_fused(
    const int* __restrict__ bcur0, const int* __restrict__ bcur2,
    uint2* __restrict__ slab0, uint2* __restrict__ slab2,
    int* __restrict__ rss0, int* __restrict__ rse0,
    int* __restrict__ rss2, int* __restrict__ rse2)
{
    __shared__ uint2 sedge[FCAP];    // 80 KB
    __shared__ int rcnt[BROWS];      // counts -> cursors
    __shared__ int psc[256];         // pair-sum scan scratch

    int b, n, cap; uint2* edges; const int* bcur; int* rss; int* rse;
    if ((int)blockIdx.x < NB0) {
        b = blockIdx.x; edges = slab0; bcur = bcur0; rss = rss0; rse = rse0;
        n = cN0; cap = CAP00;
    } else {
        b = blockIdx.x - NB0; edges = slab2; bcur = bcur2; rss = rss2; rse = rse2;
        n = cN2; cap = CAP12;
    }
    const int tid = threadIdx.x;
    const int s = b * cap;
    const int count = min(bcur[b], cap);
    const int lo = b << BROWS_LOG;
    const int nr = min(BROWS, n - lo);

    for (int r = tid; r < BROWS; r += 256) rcnt[r] = 0;
    __syncthreads();
    for (int i = tid; i < count; i += 256) {
        uint2 ed = edges[s + i];
        sedge[i] = ed;
        atomicAdd(&rcnt[ed.x >> 20], 1);
    }
    __syncthreads();

    int c0 = rcnt[2 * tid], c1 = rcnt[2 * tid + 1];
    int sum = c0 + c1;
    psc[tid] = sum;
    __syncthreads();
    for (int o = 1; o < 256; o <<= 1) {
        int x = (tid >= o) ? psc[tid - o] : 0;
        __syncthreads();
        psc[tid] += x;
        __syncthreads();
    }
    int pexcl = psc[tid] - sum;
    int e0 = pexcl, e1 = pexcl + c0;
    if (2 * tid < nr) {
        rss[lo + 2 * tid] = s + e0;
        rse[lo + 2 * tid] = s + e1;
    }
    if (2 * tid + 1 < nr) {
        rss[lo + 2 * tid + 1] = s + e1;
        rse[lo + 2 * tid + 1] = s + e1 + c1;
    }
    __syncthreads();
    rcnt[2 * tid] = e0;
    rcnt[2 * tid + 1] = e1;
    __syncthreads();

    for (int i = tid; i < count; i += 256) {
        uint2 ed = sedge[i];
        int rl = ed.x >> 20;
        int pos = atomicAdd(&rcnt[rl], 1);
        edges[s + pos] = make_uint2(ed.x & 0xFFFFFu, ed.y);
    }
}

// ---------------- Fused pull: y[r] = relu(sum_e val*h[col]), 1 wave / row ----
// global wave id w in [wbase, wbase+wcount): w < cN2 -> y2 path, else y0 path.
__global__ __launch_bounds__(256) void pull_fused(
    const int* __restrict__ rss2, const int* __restrict__ rse2,
    const uint2* __restrict__ slab2, const uint16_t* __restrict__ h12,
    float* __restrict__ y2,
    const int* __restrict__ rss0, const int* __restrict__ rse0,
    const uint2* __restrict__ slab0, const uint16_t* __restrict__ h0,
    float* __restrict__ y0,
    int wbase, int wcount)
{
    int wi = (blockIdx.x * 256 + threadIdx.x) >> 6;
    if (wi >= wcount) return;
    int w = wbase + wi;
    int l = threadIdx.x & 63;

    const int* rss; const int* rse; const uint2* edges; const uint16_t* h;
    float* y; int r;
    if (w < cN2) {
        rss = rss2; rse = rse2; edges = slab2; h = h12; y = y2; r = w;
    } else {
        rss = rss0; rse = rse0; edges = slab0; h = h0; y = y0; r = w - cN2;
    }

    int s = rss[r], e = rse[r];
    float a0 = 0.f, a1 = 0.f;
    int i = s;
    for (; i + 3 < e; i += 4) {
        uint2 e0 = edges[i], e1 = edges[i + 1], e2 = edges[i + 2], e3 = edges[i + 3];
        uint32_t p0 = *(const uint32_t*)&h[(size_t)e0.x * cD + l * 2];
        uint32_t p1 = *(const uint32_t*)&h[(size_t)e1.x * cD + l * 2];
        uint32_t p2 = *(const uint32_t*)&h[(size_t)e2.x * cD + l * 2];
        uint32_t p3 = *(const uint32_t*)&h[(size_t)e3.x * cD + l * 2];
        float v0 = __uint_as_float(e0.y), v1 = __uint_as_float(e1.y);
        float v2 = __uint_as_float(e2.y), v3 = __uint_as_float(e3.y);
        a0 = fmaf(v0, bf2f(p0 & 0xffffu), a0); a1 = fmaf(v0, bf2f(p0 >> 16), a1);
        a0 = fmaf(v1, bf2f(p1 & 0xffffu), a0); a1 = fmaf(v1, bf2f(p1 >> 16), a1);
        a0 = fmaf(v2, bf2f(p2 & 0xffffu), a0); a1 = fmaf(v2, bf2f(p2 >> 16), a1);
        a0 = fmaf(v3, bf2f(p3 & 0xffffu), a0); a1 = fmaf(v3, bf2f(p3 >> 16), a1);
    }
    for (; i < e; ++i) {
        uint2 ed = edges[i];
        uint32_t p = *(const uint32_t*)&h[(size_t)ed.x * cD + l * 2];
        float v = __uint_as_float(ed.y);
        a0 = fmaf(v, bf2f(p & 0xffffu), a0);
        a1 = fmaf(v, bf2f(p >> 16), a1);
    }
    *(float2*)&y[(size_t)r * cD + l * 2] = make_float2(fmaxf(a0, 0.f), fmaxf(a1, 0.f));
}

extern "C" void kernel_launch(void* const* d_in, const int* in_sizes, int n_in,
                              void* d_out, int out_size, void* d_ws, size_t ws_size,
                              hipStream_t stream) {
    const float* x0  = (const float*)d_in[0];
    const float* x1  = (const float*)d_in[1];
    const int*   r00 = (const int*)d_in[2];
    const int*   c00 = (const int*)d_in[3];
    const float* v00 = (const float*)d_in[4];
    const int*   r12 = (const int*)d_in[5];
    const int*   c12 = (const int*)d_in[6];
    const float* v12 = (const float*)d_in[7];
    const float* W0  = (const float*)d_in[8];
    const float* W12 = (const float*)d_in[9];

    float* out  = (float*)d_out;
    float* y0   = out;
    float* out1 = out + (size_t)cN0 * cD;
    float* y2   = out + (size_t)(cN0 + cN1) * cD;

    char* ws = (char*)d_ws;
    size_t o = 0;
    uint16_t* h0    = (uint16_t*)(ws + o); o += (size_t)cN0 * cD * 2;       // 25.6 MB
    uint2*    slab0 = (uint2*)   (ws + o); o += (size_t)NB0 * CAP00 * 8;    // 16.06 MB
    uint2*    slab2 = (uint2*)   (ws + o); o += (size_t)NB2 * CAP12 * 8;    // 2.41 MB
    int*      rss0  = (int*)     (ws + o); o += (size_t)cN0 * 4;
    int*      rse0  = (int*)     (ws + o); o += (size_t)cN0 * 4;
    int*      rss2  = (int*)     (ws + o); o += (size_t)cN2 * 4;
    int*      rse2  = (int*)     (ws + o); o += (size_t)cN2 * 4;
    int*      bcur0 = (int*)     (ws + o); o += 256 * 4;
    int*      bcur2 = (int*)     (ws + o); o += 256 * 4;
    size_t o_h12 = o;
    size_t need_h12 = o_h12 + (size_t)cN1 * cD * 2;                          // ~84 MB

    // h12 lives in ws if it fits (enables single fused pull); else it is
    // staged in the y0 region of d_out (pull(y2) must then precede pull(y0)).
    bool h12_in_ws = (ws_size >= need_h12);
    uint16_t* h12 = h12_in_ws ? (uint16_t*)(ws + o_h12) : (uint16_t*)y0;

    // 1. zero both cursor arrays (adjacent -> single tiny memset)
    hipMemsetAsync(bcur0, 0, 512 * 4, stream);

    // 2. both GEMMs, one dispatch
    gemm_fused_kernel<<<GB12 + GB00, 256, 0, stream>>>(
        x1, W12, h12, out1, x0, W0, h0);

    // 3. both partitions, one dispatch (no hist/scan pre-pass: fixed slabs)
    partition_fused<<<PB0 + PB1, 256, 0, stream>>>(
        r00, c00, v00, r12, c12, v12, bcur0, bcur2, slab0, slab2);

    // 4. both fine counting-sorts, one dispatch
    fine_fused<<<NB0 + NB2, 256, 0, stream>>>(
        bcur0, bcur2, slab0, slab2, rss0, rse0, rss2, rse2);

    // 5. pull(s)
    if (h12_in_ws) {
        int wtot = cN2 + cN0;
        pull_fused<<<(wtot + 3) / 4, 256, 0, stream>>>(
            rss2, rse2, slab2, h12, y2, rss0, rse0, slab0, h0, y0, 0, wtot);
    } else {
        pull_fused<<<(cN2 + 3) / 4, 256, 0, stream>>>(
            rss2, rse2, slab2, h12, y2, rss0, rse0, slab0, h0, y0, 0, cN2);
        pull_fused<<<(cN0 + 3) / 4, 256, 0, stream>>>(
            rss2, rse2, slab2, h12, y2, rss0, rse0, slab0, h0, y0, cN2, cN0);
    }
}